// Round 8
// baseline (114.345 us; speedup 1.0000x reference)
//
#include <hip/hip_runtime.h>

#define NB_CAT  8192
#define RANK    16
#define N_COLS  4
#define N_PAIRS 1048576

#define NSLICE      16                        // (col, rank-quarter)
#define SLICE_ROWS  NB_CAT                    // rows of 8 B (4 fp16)
#define SLICE_BYTES (SLICE_ROWS * 8)          // 64 KB
#define TBL_BYTES   ((size_t)NSLICE * SLICE_BYTES)  // 1 MB
#define LDS_BYTES   (2 * SLICE_BYTES)         // 128 KB (double buffer)

typedef _Float16 half2_t __attribute__((ext_vector_type(2)));

#if defined(__has_builtin)
#if __has_builtin(__builtin_amdgcn_fdot2)
#define HAVE_FDOT2 1
#endif
#if __has_builtin(__builtin_amdgcn_global_load_lds)
#define HAVE_DMA 1
#endif
#endif

__device__ __forceinline__ float dot4_f16(uint2 A, uint2 B, float acc) {
#ifdef HAVE_FDOT2
    acc = __builtin_amdgcn_fdot2(__builtin_bit_cast(half2_t, A.x), __builtin_bit_cast(half2_t, B.x), acc, false);
    acc = __builtin_amdgcn_fdot2(__builtin_bit_cast(half2_t, A.y), __builtin_bit_cast(half2_t, B.y), acc, false);
#else
    half2_t ax = __builtin_bit_cast(half2_t, A.x), bx = __builtin_bit_cast(half2_t, B.x);
    half2_t ay = __builtin_bit_cast(half2_t, A.y), by = __builtin_bit_cast(half2_t, B.y);
    acc = fmaf((float)ax[0], (float)bx[0], acc); acc = fmaf((float)ax[1], (float)bx[1], acc);
    acc = fmaf((float)ay[0], (float)by[0], acc); acc = fmaf((float)ay[1], (float)by[1], acc);
#endif
    return acc;
}

__device__ __forceinline__ int comp4(const int4& v, int c) {
    // c is a compile-time constant after full unroll -> folds to a register pick
    return (c == 0) ? v.x : (c == 1) ? v.y : (c == 2) ? v.z : v.w;
}

#ifdef HAVE_DMA
__device__ __forceinline__ void dma16(const void* g, void* l) {
    __builtin_amdgcn_global_load_lds(
        (const __attribute__((address_space(1))) void*)g,
        (__attribute__((address_space(3))) void*)l,
        16, 0, 0);
}
#endif

// ---------- prep: fp32 cf -> fp16 table, layout [slice=(c,qr)][cat] row = 8 B ----------
__global__ __launch_bounds__(256) void pack_f16_kernel(
    const float4* __restrict__ src, uint2* __restrict__ dst)
{
    const int g = blockIdx.x * 256 + threadIdx.x;   // slice*8192 + cat, 131072 total
    const int s = g >> 13;
    const int k = g & (NB_CAT - 1);
    const int c = s >> 2, qr = s & 3;

    const float4 f = src[(c * NB_CAT + k) * 4 + qr];
    half2_t p0 = {(_Float16)f.x, (_Float16)f.y};
    half2_t p1 = {(_Float16)f.z, (_Float16)f.w};
    uint2 u;
    u.x = __builtin_bit_cast(unsigned int, p0);
    u.y = __builtin_bit_cast(unsigned int, p1);
    dst[g] = u;
}

// ---------- main: phase loop, double-buffered ASYNC-DMA staging ----------
// 256 blocks x 1024 threads, 128 KB dyn LDS (2 x 64 KB). Phase s: issue DMA of
// slice s+1 into the other buffer (4 x global_load_lds width-16 per wave, no
// VGPR round-trip, no ds_write), compute slice s from the current buffer,
// __syncthreads (its vmcnt(0) drain lands after compute hid the DMA latency).
__global__ __launch_bounds__(1024, 1) void IndexKernel_32238024524411_kernel(
    const int4*  __restrict__ x4,    // (N_PAIRS) int4
    const int4*  __restrict__ y4,
    const uint2* __restrict__ tbl,   // fp16 table in ws
    const float* __restrict__ stdv,  // (N_COLS, NB_CAT) fp32
    float*       __restrict__ out)
{
    extern __shared__ uint2 sh[];    // 2 * SLICE_ROWS

    const int tid  = threadIdx.x;
    const int base = blockIdx.x * 4096 + tid;

    // coalesced one-time index loads (held in registers for all phases)
    int4 xv[4], yv[4];
#pragma unroll
    for (int j = 0; j < 4; ++j) {
        xv[j] = x4[base + j * 1024];
        yv[j] = y4[base + j * 1024];
    }

    float acc[4] = {0.f, 0.f, 0.f, 0.f};

    // diagonal std^2 pre-pass (rare; keeps the phase loop free of vmem)
#pragma unroll
    for (int j = 0; j < 4; ++j) {
        const int4 a = xv[j], b = yv[j];
        if (a.x == b.x) { const float s = stdv[0 * NB_CAT + a.x]; acc[j] = fmaf(s, s, acc[j]); }
        if (a.y == b.y) { const float s = stdv[1 * NB_CAT + a.y]; acc[j] = fmaf(s, s, acc[j]); }
        if (a.z == b.z) { const float s = stdv[2 * NB_CAT + a.z]; acc[j] = fmaf(s, s, acc[j]); }
        if (a.w == b.w) { const float s = stdv[3 * NB_CAT + a.w]; acc[j] = fmaf(s, s, acc[j]); }
    }

#ifdef HAVE_DMA
    // prologue: stage slice 0 into buffer 0
#pragma unroll
    for (int it = 0; it < 4; ++it) {
        const size_t off = (size_t)(tid + it * 1024) * 16;   // bytes, lane-linear
        dma16((const char*)tbl + off, (char*)sh + off);
    }
    __syncthreads();   // vmcnt(0) drain + barrier: slice 0 visible to all

#pragma unroll
    for (int s = 0; s < NSLICE; ++s) {
        const int c = s >> 2;
        if (s < NSLICE - 1) {
            // async DMA of slice s+1 into the other buffer; stays in flight
            // during compute, drained by the vmcnt(0) inside __syncthreads.
            const char* gsrc = (const char*)(tbl + (size_t)(s + 1) * SLICE_ROWS);
            char*       ldst = (char*)(sh + ((s + 1) & 1) * SLICE_ROWS);
#pragma unroll
            for (int it = 0; it < 4; ++it) {
                const size_t off = (size_t)(tid + it * 1024) * 16;
                dma16(gsrc + off, ldst + off);
            }
        }
        const uint2* buf = sh + (s & 1) * SLICE_ROWS;
#pragma unroll
        for (int j = 0; j < 4; ++j) {
            const int xi = comp4(xv[j], c);
            const int yi = comp4(yv[j], c);
            const uint2 a = buf[xi];
            const uint2 b = buf[yi];
            acc[j] = dot4_f16(a, b, acc[j]);
        }
        __syncthreads();
    }
#else
    // register round-trip staging fallback (R7 structure, simplified)
    uint2 stg[8];
#pragma unroll
    for (int it = 0; it < 8; ++it) stg[it] = tbl[tid + it * 1024];
#pragma unroll
    for (int s = 0; s < NSLICE; ++s) {
        const int c = s >> 2;
        uint2* buf = sh + (s & 1) * SLICE_ROWS;
#pragma unroll
        for (int it = 0; it < 8; ++it) buf[tid + it * 1024] = stg[it];
        if (s < NSLICE - 1) {
            const uint2* nsrc = tbl + (size_t)(s + 1) * SLICE_ROWS;
#pragma unroll
            for (int it = 0; it < 8; ++it) stg[it] = nsrc[tid + it * 1024];
        }
        __syncthreads();
#pragma unroll
        for (int j = 0; j < 4; ++j) {
            const int xi = comp4(xv[j], c);
            const int yi = comp4(yv[j], c);
            acc[j] = dot4_f16(buf[xi], buf[yi], acc[j]);
        }
        __syncthreads();
    }
#endif

#pragma unroll
    for (int j = 0; j < 4; ++j) {
        out[base + j * 1024] = acc[j];
    }
}

// ---------- fallback (fp32 direct gather, R3 structure) if ws too small ----------
__global__ __launch_bounds__(256) void fallback_kernel(
    const int* __restrict__ x, const int* __restrict__ y,
    const float4* __restrict__ cf, const float* __restrict__ stdv,
    float* __restrict__ out)
{
    const int tid = threadIdx.x;
    const int q = tid & 15, gi = tid >> 4, c = q >> 2, s = q & 3;
    const int p0 = blockIdx.x * 32 + gi, p1 = p0 + 16;
    const int rb = c * NB_CAT;
    const int xi0 = x[p0*4+c], yi0 = y[p0*4+c], xi1 = x[p1*4+c], yi1 = y[p1*4+c];
    const float4 a0 = cf[(size_t)(rb+xi0)*4 + s], b0 = cf[(size_t)(rb+yi0)*4 + s];
    const float4 a1 = cf[(size_t)(rb+xi1)*4 + s], b1 = cf[(size_t)(rb+yi1)*4 + s];
    float v0 = a0.x*b0.x; v0 = fmaf(a0.y,b0.y,v0); v0 = fmaf(a0.z,b0.z,v0); v0 = fmaf(a0.w,b0.w,v0);
    float v1 = a1.x*b1.x; v1 = fmaf(a1.y,b1.y,v1); v1 = fmaf(a1.z,b1.z,v1); v1 = fmaf(a1.w,b1.w,v1);
    if (s == 0 && xi0 == yi0) { float sd = stdv[rb+xi0]; v0 = fmaf(sd,sd,v0); }
    if (s == 0 && xi1 == yi1) { float sd = stdv[rb+yi1]; v1 = fmaf(sd,sd,v1); }
    int t;
    t = __builtin_amdgcn_update_dpp(0, __float_as_int(v0), 0xB1, 0xF, 0xF, true); v0 += __int_as_float(t);
    t = __builtin_amdgcn_update_dpp(0, __float_as_int(v0), 0x4E, 0xF, 0xF, true); v0 += __int_as_float(t);
    t = __builtin_amdgcn_update_dpp(0, __float_as_int(v0), 0x141,0xF, 0xF, true); v0 += __int_as_float(t);
    t = __builtin_amdgcn_update_dpp(0, __float_as_int(v0), 0x128,0xF, 0xF, true); v0 += __int_as_float(t);
    t = __builtin_amdgcn_update_dpp(0, __float_as_int(v1), 0xB1, 0xF, 0xF, true); v1 += __int_as_float(t);
    t = __builtin_amdgcn_update_dpp(0, __float_as_int(v1), 0x4E, 0xF, 0xF, true); v1 += __int_as_float(t);
    t = __builtin_amdgcn_update_dpp(0, __float_as_int(v1), 0x141,0xF, 0xF, true); v1 += __int_as_float(t);
    t = __builtin_amdgcn_update_dpp(0, __float_as_int(v1), 0x128,0xF, 0xF, true); v1 += __int_as_float(t);
    if (q == 0) { out[p0] = v0; out[p1] = v1; }
}

extern "C" void kernel_launch(void* const* d_in, const int* in_sizes, int n_in,
                              void* d_out, int out_size, void* d_ws, size_t ws_size,
                              hipStream_t stream) {
    const int*   x    = (const int*)d_in[0];
    const int*   y    = (const int*)d_in[1];
    const float* cf   = (const float*)d_in[2];
    const float* stdv = (const float*)d_in[3];
    float*       out  = (float*)d_out;

    if (ws_size < TBL_BYTES) {
        fallback_kernel<<<N_PAIRS / 32, 256, 0, stream>>>(
            x, y, (const float4*)cf, stdv, out);
        return;
    }

    (void)hipFuncSetAttribute(
        reinterpret_cast<const void*>(&IndexKernel_32238024524411_kernel),
        hipFuncAttributeMaxDynamicSharedMemorySize, LDS_BYTES);

    pack_f16_kernel<<<NSLICE * NB_CAT / 256, 256, 0, stream>>>(
        (const float4*)cf, (uint2*)d_ws);

    IndexKernel_32238024524411_kernel<<<N_PAIRS / 4096, 1024, LDS_BYTES, stream>>>(
        (const int4*)x, (const int4*)y, (const uint2*)d_ws, stdv, out);
}

// Round 9
// 95.894 us; speedup vs baseline: 1.1924x; 1.1924x over previous
//
#include <hip/hip_runtime.h>

#define NB_CAT  8192
#define RANK    16
#define N_COLS  4
#define N_PAIRS 1048576

#define NSLICE      16                        // (col, rank-quarter)
#define SLICE_ROWS  NB_CAT                    // rows of 8 B (4 fp16)
#define SLICE_BYTES (SLICE_ROWS * 8)          // 64 KB
#define TBL_BYTES   ((size_t)NSLICE * SLICE_BYTES)   // 1 MB
#define LDS_BYTES   (2 * SLICE_BYTES)         // 128 KB (double buffer)
#define PART_BYTES  ((size_t)N_PAIRS * 4)     // 4 MB per partial
#define WS_NEED     (TBL_BYTES + 2 * PART_BYTES)     // 9 MB

typedef _Float16 half2_t __attribute__((ext_vector_type(2)));

#if defined(__has_builtin)
#if __has_builtin(__builtin_amdgcn_fdot2)
#define HAVE_FDOT2 1
#endif
#endif

__device__ __forceinline__ float dot4_f16(uint2 A, uint2 B, float acc) {
#ifdef HAVE_FDOT2
    acc = __builtin_amdgcn_fdot2(__builtin_bit_cast(half2_t, A.x), __builtin_bit_cast(half2_t, B.x), acc, false);
    acc = __builtin_amdgcn_fdot2(__builtin_bit_cast(half2_t, A.y), __builtin_bit_cast(half2_t, B.y), acc, false);
#else
    half2_t ax = __builtin_bit_cast(half2_t, A.x), bx = __builtin_bit_cast(half2_t, B.x);
    half2_t ay = __builtin_bit_cast(half2_t, A.y), by = __builtin_bit_cast(half2_t, B.y);
    acc = fmaf((float)ax[0], (float)bx[0], acc); acc = fmaf((float)ax[1], (float)bx[1], acc);
    acc = fmaf((float)ay[0], (float)by[0], acc); acc = fmaf((float)ay[1], (float)by[1], acc);
#endif
    return acc;
}

// ---------- prep: fp32 cf -> fp16 table, layout [slice=(c,qr)][cat] row = 8 B ----------
__global__ __launch_bounds__(256) void pack_f16_kernel(
    const float4* __restrict__ src, uint2* __restrict__ dst)
{
    const int g = blockIdx.x * 256 + threadIdx.x;   // slice*8192 + cat, 131072 total
    const int s = g >> 13;
    const int k = g & (NB_CAT - 1);
    const int c = s >> 2, qr = s & 3;

    const float4 f = src[(c * NB_CAT + k) * 4 + qr];
    half2_t p0 = {(_Float16)f.x, (_Float16)f.y};
    half2_t p1 = {(_Float16)f.z, (_Float16)f.w};
    uint2 u;
    u.x = __builtin_bit_cast(unsigned int, p0);
    u.y = __builtin_bit_cast(unsigned int, p1);
    dst[g] = u;
}

// ---------- main: column-split (2 cols/block) + pipelined double-buffer staging ----------
// 256 blocks x 1024 threads, 128 KB dyn LDS. blockIdx = group*128 + chunk.
// Group g handles cols {2g, 2g+1} = table slices [8g, 8g+8) = 512 KB staged over
// 8 phases (vs R7's 1 MB / 16 phases). Per phase: ds_write slice s from regs,
// prefetch slice s+1 into regs (global loads stay in flight ACROSS the raw
// lgkm-only barrier), barrier, gather-compute. Partial sums -> ws; reduce adds.
__global__ __launch_bounds__(1024, 1) void IndexKernel_32238024524411_kernel(
    const int2*  __restrict__ x2,    // (N_PAIRS, 2) int2; element 2p+g = cols {2g,2g+1}
    const int2*  __restrict__ y2,
    const uint2* __restrict__ tbl,   // fp16 table in ws
    const float* __restrict__ stdv,  // (N_COLS, NB_CAT) fp32
    float*       __restrict__ part)  // (2, N_PAIRS) partials in ws
{
    extern __shared__ uint2 sh[];    // 2 * SLICE_ROWS

    const int tid   = threadIdx.x;
    const int g     = blockIdx.x >> 7;     // col-group 0/1
    const int chunk = blockIdx.x & 127;
    const int base  = chunk * 8192 + tid;  // pairs: base + j*1024, j=0..7

    const uint2* gtbl = tbl + (size_t)(g * 8) * SLICE_ROWS;

    // coalesced-ish one-time index loads (8 B per lane, stride 16 B)
    int2 xi[8], yi[8];
#pragma unroll
    for (int j = 0; j < 8; ++j) {
        const size_t p = (size_t)(base + j * 1024);
        xi[j] = x2[p * 2 + g];
        yi[j] = y2[p * 2 + g];
    }

    float acc[8] = {0.f, 0.f, 0.f, 0.f, 0.f, 0.f, 0.f, 0.f};

    // diagonal std^2 pre-pass for this group's two columns
    const float* sd0 = stdv + (size_t)(2 * g) * NB_CAT;
    const float* sd1 = stdv + (size_t)(2 * g + 1) * NB_CAT;
#pragma unroll
    for (int j = 0; j < 8; ++j) {
        if (xi[j].x == yi[j].x) { const float s = sd0[xi[j].x]; acc[j] = fmaf(s, s, acc[j]); }
        if (xi[j].y == yi[j].y) { const float s = sd1[xi[j].y]; acc[j] = fmaf(s, s, acc[j]); }
    }

    // preload slice 0 into staging registers
    uint2 stg[8];
#pragma unroll
    for (int it = 0; it < 8; ++it) stg[it] = gtbl[tid + it * 1024];

#define PHASE(S)                                                               \
    {                                                                          \
        constexpr int s  = (S);                                                \
        constexpr int cl = s >> 2;   /* local col 0/1 */                       \
        uint2* buf = sh + (s & 1) * SLICE_ROWS;                                \
        _Pragma("unroll")                                                      \
        for (int it = 0; it < 8; ++it) buf[tid + it * 1024] = stg[it];         \
        if (s < 7) {                                                           \
            const uint2* nsrc = gtbl + (size_t)(s + 1) * SLICE_ROWS;           \
            _Pragma("unroll")                                                  \
            for (int it = 0; it < 8; ++it) stg[it] = nsrc[tid + it * 1024];    \
        }                                                                      \
        /* raw barrier: wait LDS writes only; prefetch stays in flight */      \
        asm volatile("s_waitcnt lgkmcnt(0)" ::: "memory");                     \
        __builtin_amdgcn_s_barrier();                                          \
        asm volatile("" ::: "memory");                                         \
        _Pragma("unroll")                                                      \
        for (int j = 0; j < 8; ++j) {                                          \
            const int a = cl ? xi[j].y : xi[j].x;                              \
            const int b = cl ? yi[j].y : yi[j].x;                              \
            acc[j] = dot4_f16(buf[a], buf[b], acc[j]);                         \
        }                                                                      \
        asm volatile("" ::: "memory");                                         \
    }

    PHASE(0) PHASE(1) PHASE(2) PHASE(3)
    PHASE(4) PHASE(5) PHASE(6) PHASE(7)
#undef PHASE

    float* my = part + (size_t)g * N_PAIRS;
#pragma unroll
    for (int j = 0; j < 8; ++j) {
        my[base + j * 1024] = acc[j];
    }
}

// ---------- reduce: out = part0 + part1 ----------
__global__ __launch_bounds__(256) void reduce_kernel(
    const float4* __restrict__ p0, const float4* __restrict__ p1,
    float4* __restrict__ out)
{
    const int i = blockIdx.x * 256 + threadIdx.x;
    const float4 a = p0[i];
    const float4 b = p1[i];
    out[i] = float4{a.x + b.x, a.y + b.y, a.z + b.z, a.w + b.w};
}

// ---------- fallback (fp32 direct gather, R3 structure) if ws too small ----------
__global__ __launch_bounds__(256) void fallback_kernel(
    const int* __restrict__ x, const int* __restrict__ y,
    const float4* __restrict__ cf, const float* __restrict__ stdv,
    float* __restrict__ out)
{
    const int tid = threadIdx.x;
    const int q = tid & 15, gi = tid >> 4, c = q >> 2, s = q & 3;
    const int p0 = blockIdx.x * 32 + gi, p1 = p0 + 16;
    const int rb = c * NB_CAT;
    const int xi0 = x[p0*4+c], yi0 = y[p0*4+c], xi1 = x[p1*4+c], yi1 = y[p1*4+c];
    const float4 a0 = cf[(size_t)(rb+xi0)*4 + s], b0 = cf[(size_t)(rb+yi0)*4 + s];
    const float4 a1 = cf[(size_t)(rb+xi1)*4 + s], b1 = cf[(size_t)(rb+yi1)*4 + s];
    float v0 = a0.x*b0.x; v0 = fmaf(a0.y,b0.y,v0); v0 = fmaf(a0.z,b0.z,v0); v0 = fmaf(a0.w,b0.w,v0);
    float v1 = a1.x*b1.x; v1 = fmaf(a1.y,b1.y,v1); v1 = fmaf(a1.z,b1.z,v1); v1 = fmaf(a1.w,b1.w,v1);
    if (s == 0 && xi0 == yi0) { float sd = stdv[rb+xi0]; v0 = fmaf(sd,sd,v0); }
    if (s == 0 && xi1 == yi1) { float sd = stdv[rb+yi1]; v1 = fmaf(sd,sd,v1); }
    int t;
    t = __builtin_amdgcn_update_dpp(0, __float_as_int(v0), 0xB1, 0xF, 0xF, true); v0 += __int_as_float(t);
    t = __builtin_amdgcn_update_dpp(0, __float_as_int(v0), 0x4E, 0xF, 0xF, true); v0 += __int_as_float(t);
    t = __builtin_amdgcn_update_dpp(0, __float_as_int(v0), 0x141,0xF, 0xF, true); v0 += __int_as_float(t);
    t = __builtin_amdgcn_update_dpp(0, __float_as_int(v0), 0x128,0xF, 0xF, true); v0 += __int_as_float(t);
    t = __builtin_amdgcn_update_dpp(0, __float_as_int(v1), 0xB1, 0xF, 0xF, true); v1 += __int_as_float(t);
    t = __builtin_amdgcn_update_dpp(0, __float_as_int(v1), 0x4E, 0xF, 0xF, true); v1 += __int_as_float(t);
    t = __builtin_amdgcn_update_dpp(0, __float_as_int(v1), 0x141,0xF, 0xF, true); v1 += __int_as_float(t);
    t = __builtin_amdgcn_update_dpp(0, __float_as_int(v1), 0x128,0xF, 0xF, true); v1 += __int_as_float(t);
    if (q == 0) { out[p0] = v0; out[p1] = v1; }
}

extern "C" void kernel_launch(void* const* d_in, const int* in_sizes, int n_in,
                              void* d_out, int out_size, void* d_ws, size_t ws_size,
                              hipStream_t stream) {
    const int*   x    = (const int*)d_in[0];
    const int*   y    = (const int*)d_in[1];
    const float* cf   = (const float*)d_in[2];
    const float* stdv = (const float*)d_in[3];
    float*       out  = (float*)d_out;

    if (ws_size < WS_NEED) {
        fallback_kernel<<<N_PAIRS / 32, 256, 0, stream>>>(
            x, y, (const float4*)cf, stdv, out);
        return;
    }

    (void)hipFuncSetAttribute(
        reinterpret_cast<const void*>(&IndexKernel_32238024524411_kernel),
        hipFuncAttributeMaxDynamicSharedMemorySize, LDS_BYTES);

    uint2* tbl   = (uint2*)d_ws;
    float* part  = (float*)((char*)d_ws + TBL_BYTES);   // (2, N_PAIRS)

    pack_f16_kernel<<<NSLICE * NB_CAT / 256, 256, 0, stream>>>(
        (const float4*)cf, tbl);

    IndexKernel_32238024524411_kernel<<<256, 1024, LDS_BYTES, stream>>>(
        (const int2*)x, (const int2*)y, tbl, stdv, part);

    reduce_kernel<<<N_PAIRS / 4 / 256, 256, 0, stream>>>(
        (const float4*)part, (const float4*)(part + N_PAIRS), (float4*)out);
}